// Round 1
// baseline (107.221 us; speedup 1.0000x reference)
//
#include <hip/hip_runtime.h>
#include <stdint.h>

// Problem constants (fixed by the reference)
#define B_IMG        64
#define M_GT         100
#define N_PROP       4000
#define K_TOT        4100          // N + M (proposal_append_gt)
#define NUM_CLASSES_ 80
#define BATCH_PER    512
#define NUM_FG_TGT   128
#define OUT_STRIDE   (B_IMG * BATCH_PER)   // 32768 elements per output tensor

// Kernel 1 (match) geometry: 2-lane m-split.
// R13: grid is now EXACTLY 2048 blocks = 8 blocks/CU x 256 CUs -> single
// scheduling round (2112 blocks left a 64-block straggler round that doubled
// the match wall, since select's graph edge waits for ALL match blocks).
// The 4 leftover elements per image (4096..4099) ride on lanes 0-1 of blocks
// q<4 (one extra inner loop on 4/32 blocks ~ +1us straggle vs +8us full round).
#define NT1          256
#define BPI1         32                    // blocks per image (32*128 = 4096)
#define EPB1         128                   // elements per block (2 lanes/elem)
// Kernel 2 (select) geometry
#define NTH          1024
#define HALF_CAP     1024
#define NTF          1024                  // fallback kernel threads

// Key packing (uint64 compare gives exact (fg, pri, idx) descending order;
// midx rides in the low bits — idx is unique so it never affects ordering):
//   bit 50      : fg flag
//   bits 49..20 : float bits of priority (pri in [0,1) => bits < 2^30)
//   bits 19..7  : element index (0..4099 < 8192)  — reproduces the reversed-
//                 stable-argsort tiebreak (higher idx first on equal pri)
//   bits  6..0  : matched gt index (0..99 < 128)

// IoU, contraction off, branchless: uni > 0 always (box wh >= 8 => areas > 0)
// and inter==0 gives +0.0/uni == +0.0 — bit-identical to the reference's
// where(inter>0, inter/uni, 0). Validated absmax-0 in R12.
__device__ __forceinline__ float iou_g(float4 g,
                                       float bx1, float by1, float bx2, float by2,
                                       float area_b) {
#pragma clang fp contract(off)
    float area_a = (g.z - g.x) * (g.w - g.y);
    float ltx = fmaxf(g.x, bx1), lty = fmaxf(g.y, by1);
    float rbx = fminf(g.z, bx2), rby = fminf(g.w, by2);
    float wx = fmaxf(rbx - ltx, 0.0f);
    float wy = fmaxf(rby - lty, 0.0f);
    float inter = wx * wy;
    float uni = area_a + area_b - inter;
    return inter / uni;
}

// Same fp ops, but area_a supplied (precomputed once per gt box with the
// identical (z-x)*(w-y) contract-off expression => bit-identical result,
// saves 3 VALU instrs per inner-loop iteration in match).
__device__ __forceinline__ float iou_area(float4 g, float area_a,
                                          float bx1, float by1, float bx2, float by2,
                                          float area_b) {
#pragma clang fp contract(off)
    float ltx = fmaxf(g.x, bx1), lty = fmaxf(g.y, by1);
    float rbx = fminf(g.z, bx2), rby = fminf(g.w, by2);
    float wx = fmaxf(rbx - ltx, 0.0f);
    float wy = fmaxf(rby - lty, 0.0f);
    float inter = wx * wy;
    float uni = area_a + area_b - inter;
    return inter / uni;
}

// One element's match: 2 lanes (half 0: m in [0,50), half 1: [50,100)),
// combined with one __shfl_xor — upper half wins only on strict > which
// reproduces sequential first-occurrence argmax (validated absmax-0 in R12).
__device__ __forceinline__ void match_one(
        int b, int e, int half,
        const float4* s_gtb4, const float* s_area,
        const float* __restrict__ prop_boxes,
        const float* __restrict__ rand_pri,
        uint64_t*    __restrict__ keys) {
    const uint32_t pb = __float_as_uint(rand_pri[(size_t)b * K_TOT + e]);
    float4 bp;
    if (e < N_PROP)
        bp = *(const float4*)(prop_boxes + ((size_t)b * N_PROP + e) * 4);
    else
        bp = s_gtb4[e - N_PROP];
    float area_b;
    {
#pragma clang fp contract(off)
        area_b = (bp.z - bp.x) * (bp.w - bp.y);
    }
    const int mlo = half * (M_GT / 2);
    float best = -1.0f; int bidx = mlo;
#pragma unroll 2
    for (int m = mlo; m < mlo + M_GT / 2; ++m) {
        float iv = iou_area(s_gtb4[m], s_area[m], bp.x, bp.y, bp.z, bp.w, area_b);
        if (iv > best) { best = iv; bidx = m; }    // strict > => first max in half
    }
    // combine halves: upper wins only on strict > (== sequential argmax)
    const float ob = __shfl_xor(best, 1);
    const int   oi = __shfl_xor(bidx, 1);
    if (half == 0) {
        if (ob > best) { best = ob; bidx = oi; }
        const bool fg = best >= 0.5f;
        uint64_t key = (fg ? (1ull << 50) : 0ull)
                     | ((uint64_t)pb << 20)
                     | ((uint64_t)e  << 7)
                     | (uint64_t)bidx;
        // AGENT-COHERENT store: visibility to kernel 2 does not depend on
        // runtime inter-kernel cache maintenance (graph replay elides it —
        // the diagnosed cause of R3's replay-only divergence).
        __hip_atomic_store(&keys[(size_t)b * K_TOT + e], key,
                           __ATOMIC_RELAXED, __HIP_MEMORY_SCOPE_AGENT);
    }
}

// ---------------------------------------------------------------------------
// Kernel 1: IoU argmax + key build. Grid = 64 x 32 blocks x 256 threads
// (exactly 8 blocks/CU x 256 CUs => one scheduling round, no straggler).
// 8 blocks/CU at 2 KB LDS => ~8 concurrent divide-chains per SIMD, C=50 —
// hides the per-iteration dependent chain that latency-bound R4-R12.
// ---------------------------------------------------------------------------
__global__ __launch_bounds__(NT1, 8) void match_kernel(
        const float* __restrict__ gt_boxes,    // [B, M, 4]
        const float* __restrict__ prop_boxes,  // [B, N, 4]
        const float* __restrict__ rand_pri,    // [B, K]
        uint64_t*    __restrict__ keys)        // [B, K] ws
{
    __shared__ float4 s_gtb4[M_GT];            // 1.6 KB
    __shared__ float  s_area[M_GT];            // 0.4 KB

    const int blk = blockIdx.x;
    const int b   = blk >> 5;                  // image (blk / 32)
    const int q   = blk & 31;                  // slice
    const int tid = threadIdx.x;

    for (int i = tid; i < M_GT; i += NT1) {
        float4 g = ((const float4*)gt_boxes)[(size_t)b * M_GT + i];
        s_gtb4[i] = g;
        {
#pragma clang fp contract(off)
            s_area[i] = (g.z - g.x) * (g.w - g.y);   // bit-identical to per-lane
        }
    }
    __syncthreads();

    const int half = tid & 1;                  // 0: m in [0,50), 1: [50,100)
    const int e    = q * EPB1 + (tid >> 1);    // always < 4096 => no bounds check
    match_one(b, e, half, s_gtb4, s_area, prop_boxes, rand_pri, keys);

    // leftover elements 4096..4099: block q<4 handles element 4096+q on
    // lanes 0,1 (an xor-1 shuffle pair, same wave)
    if (q < 4 && tid < 2)
        match_one(b, 4096 + q, half, s_gtb4, s_area, prop_boxes, rand_pri, keys);
}

// ---------------------------------------------------------------------------
// Kernel 2: exact top-k select + rank + emit. Grid = 64 blocks x 1024 thr.
// Entry acquire fence invalidates any stale L1/L2 lines this XCD cached in a
// previous graph replay (keys were written coherently by kernel 1; the graph
// edge orders execution). R13: compaction atomics are wave-aggregated (one
// LDS atomicAdd per wave per group instead of ~530 serialized same-address
// adds) — safe because slot assignment is order-independent (rank pass).
// ---------------------------------------------------------------------------
__global__ __launch_bounds__(NTH) void select_kernel(
        const float* __restrict__ gt_boxes,    // [B, M, 4]
        const float* __restrict__ prop_boxes,  // [B, N, 4]
        const int*   __restrict__ gt_classes,  // [B, M]
        const uint64_t* __restrict__ keys,     // [B, K] ws
        float*       __restrict__ out)         // 5 x [B, 512] flat
{
    __shared__ uint64_t s_keys[K_TOT];         // 32.8 KB
    __shared__ uint64_t s_cand[2 * HALF_CAP];  // 16 KB: fg half | bg half
    __shared__ int      s_hist[2][256];        // 2 KB
    __shared__ float4   s_gtb4[M_GT];
    __shared__ int      s_gtc[M_GT];
    __shared__ float    s_out[5][BATCH_PER];   // 10 KB staging
    __shared__ int      s_T[2], s_needed[2], s_cnt[2];

    const int b   = blockIdx.x;
    const int tid = threadIdx.x;

    __builtin_amdgcn_fence(__ATOMIC_ACQUIRE, "agent");  // drop stale cache lines

    for (int i = tid; i < 512; i += NTH) s_hist[i >> 8][i & 255] = 0;
    if (tid < 2) s_cnt[tid] = 0;
    for (int i = tid; i < M_GT; i += NTH) {
        s_gtb4[i] = ((const float4*)gt_boxes)[(size_t)b * M_GT + i];
        s_gtc[i]  = gt_classes[(size_t)b * M_GT + i];
    }
    __syncthreads();

    // stage keys + histogram per group
    for (int k = tid; k < K_TOT; k += NTH) {
        uint64_t key = keys[(size_t)b * K_TOT + k];
        s_keys[k] = key;
        int g = ((key >> 50) & 1ull) ? 0 : 1;   // 0 = fg, 1 = bg
        uint32_t pbits = (uint32_t)((key >> 20) & 0x3FFFFFFFull);
        int bucket = min(255, (int)(__uint_as_float(pbits) * 256.0f));  // monotone
        atomicAdd(&s_hist[g][bucket], 1);
    }
    __syncthreads();

    // Hillis-Steele suffix scan over each 256-bucket histogram
    for (int d = 1; d < 256; d <<= 1) {
        int v = 0, g = tid >> 8, t = tid & 255;
        bool act = (tid < 512) && (t + d < 256);
        if (act) v = s_hist[g][t + d];
        __syncthreads();
        if (act) s_hist[g][t] += v;
        __syncthreads();
    }

    if (tid == 0) {
        int fg_total = s_hist[0][0];
        int bg_total = s_hist[1][0];
        int nfg = min(NUM_FG_TGT, fg_total);
        int nbg = min(BATCH_PER - nfg, bg_total);
        s_needed[0] = nfg; s_needed[1] = nbg;
    }
    __syncthreads();

    // bucket threshold: max t with S[t] >= need (unique crossing)
    if (tid < 512) {
        int g = tid >> 8, t = tid & 255;
        int need = s_needed[g];
        int St  = s_hist[g][t];
        int St1 = (t == 255) ? -1 : s_hist[g][t + 1];
        if (St >= need && St1 < need) s_T[g] = t;
    }
    if (tid < BATCH_PER) {                     // prefill invalid pattern
        s_out[0][tid] = 0.0f; s_out[1][tid] = -1.0f;
        s_out[2][tid] = -1.0f; s_out[3][tid] = -1.0f;
    }
    __syncthreads();

    const int nfg = s_needed[0], nbg = s_needed[1];
    if (tid < BATCH_PER)
        s_out[4][tid] = (tid < nfg + nbg) ? 1.0f : 0.0f;

    // compaction into disjoint halves (fg -> [0,HALF_CAP), bg -> [HALF_CAP,...)),
    // wave-aggregated: one atomicAdd per wave per group
    for (int k = tid; k < K_TOT; k += NTH) {
        uint64_t key = s_keys[k];
        int g = ((key >> 50) & 1ull) ? 0 : 1;
        uint32_t pbits = (uint32_t)((key >> 20) & 0x3FFFFFFFull);
        int bucket = min(255, (int)(__uint_as_float(pbits) * 256.0f));
        bool want = (bucket >= s_T[g]);
        const int lane = tid & 63;
        const unsigned long long lt_mask =
            (lane == 0) ? 0ull : (~0ull >> (64 - lane));
#pragma unroll
        for (int gg = 0; gg < 2; ++gg) {
            bool pred = want && (g == gg);
            unsigned long long mask = __ballot(pred);
            if (mask) {                         // wave-uniform branch
                int leader = __ffsll((long long)mask) - 1;
                int prefix = __popcll(mask & lt_mask);
                int base;
                if (pred && prefix == 0)
                    base = atomicAdd(&s_cnt[gg], __popcll(mask));
                base = __shfl(base, leader);
                if (pred) {
                    int pos = base + prefix;
                    if (pos < HALF_CAP) s_cand[gg * HALF_CAP + pos] = key;
                }
            }
        }
    }
    __syncthreads();

    // rank within each half (keys unique -> each slot written exactly once,
    // independent of atomic ordering) and emit
    const int fgc = min(s_cnt[0], HALF_CAP);
    const int bgc = min(s_cnt[1], HALF_CAP);
    for (int c = tid; c < fgc + bgc; c += NTH) {
        const bool isfg = (c < fgc);
        const int  base = isfg ? 0 : HALF_CAP;
        const int  cnt  = isfg ? fgc : bgc;
        const int  ci   = isfg ? c : (c - fgc);
        const uint64_t kc = s_cand[base + ci];
        int r = 0;
        for (int j = 0; j < cnt; ++j)          // broadcast LDS reads
            r += (s_cand[base + j] > kc) ? 1 : 0;
        int slot = -1;
        if (isfg) { if (r < nfg) slot = r; }
        else      { if (r < nbg) slot = nfg + r; }
        if (slot >= 0) {
            int idx = (int)((kc >> 7) & 0x1FFFull);
            int mi  = (int)(kc & 0x7Full);
            float4 bp;
            if (idx < N_PROP)
                bp = *(const float4*)(prop_boxes + ((size_t)b * N_PROP + idx) * 4);
            else
                bp = s_gtb4[idx - N_PROP];
            float area_b;
            {
#pragma clang fp contract(off)
                area_b = (bp.z - bp.x) * (bp.w - bp.y);
            }
            // bit-exact matched_vals[idx]: same fp ops on same inputs as K1
            float iou = iou_g(s_gtb4[mi], bp.x, bp.y, bp.z, bp.w, area_b);
            s_out[0][slot] = iou;
            s_out[1][slot] = (float)idx;
            s_out[2][slot] = (float)(isfg ? s_gtc[mi] : NUM_CLASSES_);
            s_out[3][slot] = (float)mi;
        }
    }
    __syncthreads();

    // coalesced write-out
    for (int i = tid; i < 5 * BATCH_PER; i += NTH) {
        int o = i / BATCH_PER, p = i % BATCH_PER;
        out[(size_t)o * OUT_STRIDE + (size_t)b * BATCH_PER + p] = s_out[o][p];
    }
}

// ---------------------------------------------------------------------------
// Fallback: proven single kernel (one block per image, zero workspace).
// Used only if ws_size is too small for the key buffer.
// ---------------------------------------------------------------------------
__global__ __launch_bounds__(NTF) void roiheads_fallback(
        const float* __restrict__ gt_boxes,
        const float* __restrict__ prop_boxes,
        const int*   __restrict__ gt_classes,
        const float* __restrict__ rand_pri,
        float*       __restrict__ out)
{
    __shared__ uint64_t s_keys[K_TOT];
    __shared__ uint64_t s_cand[2 * HALF_CAP];
    __shared__ int      s_hist[2][256];
    __shared__ float4   s_gtb4[M_GT];
    __shared__ int      s_gtc[M_GT];
    __shared__ float    s_out[5][BATCH_PER];
    __shared__ int      s_T[2], s_needed[2], s_cnt[2];

    const int b   = blockIdx.x;
    const int tid = threadIdx.x;

    for (int i = tid; i < 512; i += NTF) s_hist[i >> 8][i & 255] = 0;
    if (tid < 2) s_cnt[tid] = 0;
    for (int i = tid; i < M_GT; i += NTF) {
        s_gtb4[i] = ((const float4*)gt_boxes)[(size_t)b * M_GT + i];
        s_gtc[i]  = gt_classes[(size_t)b * M_GT + i];
    }
    __syncthreads();

    for (int k = tid; k < K_TOT; k += NTF) {
        float4 bp;
        if (k < N_PROP)
            bp = *(const float4*)(prop_boxes + ((size_t)b * N_PROP + k) * 4);
        else
            bp = s_gtb4[k - N_PROP];
        float area_b;
        {
#pragma clang fp contract(off)
            area_b = (bp.z - bp.x) * (bp.w - bp.y);
        }
        float best = -1.0f; int bidx = 0;
        for (int m = 0; m < M_GT; ++m) {
            float iv = iou_g(s_gtb4[m], bp.x, bp.y, bp.z, bp.w, area_b);
            if (iv > best) { best = iv; bidx = m; }
        }
        const bool fg = best >= 0.5f;
        const float pri = rand_pri[(size_t)b * K_TOT + k];
        const uint32_t pb = __float_as_uint(pri);
        s_keys[k] = (fg ? (1ull << 50) : 0ull)
                  | ((uint64_t)pb << 20)
                  | ((uint64_t)k  << 7)
                  | (uint64_t)bidx;
        int bucket = min(255, (int)(pri * 256.0f));
        atomicAdd(&s_hist[fg ? 0 : 1][bucket], 1);
    }
    __syncthreads();

    for (int d = 1; d < 256; d <<= 1) {
        int v = 0, g = tid >> 8, t = tid & 255;
        bool act = (tid < 512) && (t + d < 256);
        if (act) v = s_hist[g][t + d];
        __syncthreads();
        if (act) s_hist[g][t] += v;
        __syncthreads();
    }

    if (tid == 0) {
        int fg_total = s_hist[0][0];
        int bg_total = s_hist[1][0];
        int nfg = min(NUM_FG_TGT, fg_total);
        int nbg = min(BATCH_PER - nfg, bg_total);
        s_needed[0] = nfg; s_needed[1] = nbg;
    }
    __syncthreads();

    if (tid < 512) {
        int g = tid >> 8, t = tid & 255;
        int need = s_needed[g];
        int St  = s_hist[g][t];
        int St1 = (t == 255) ? -1 : s_hist[g][t + 1];
        if (St >= need && St1 < need) s_T[g] = t;
    }
    if (tid < BATCH_PER) {
        s_out[0][tid] = 0.0f; s_out[1][tid] = -1.0f;
        s_out[2][tid] = -1.0f; s_out[3][tid] = -1.0f;
    }
    __syncthreads();

    const int nfg = s_needed[0], nbg = s_needed[1];
    if (tid < BATCH_PER)
        s_out[4][tid] = (tid < nfg + nbg) ? 1.0f : 0.0f;

    for (int k = tid; k < K_TOT; k += NTF) {
        uint64_t key = s_keys[k];
        int g = ((key >> 50) & 1ull) ? 0 : 1;
        uint32_t pbits = (uint32_t)((key >> 20) & 0x3FFFFFFFull);
        int bucket = min(255, (int)(__uint_as_float(pbits) * 256.0f));
        if (bucket >= s_T[g]) {
            int pos = atomicAdd(&s_cnt[g], 1);
            if (pos < HALF_CAP) s_cand[g * HALF_CAP + pos] = key;
        }
    }
    __syncthreads();

    const int fgc = min(s_cnt[0], HALF_CAP);
    const int bgc = min(s_cnt[1], HALF_CAP);
    for (int c = tid; c < fgc + bgc; c += NTF) {
        const bool isfg = (c < fgc);
        const int  base = isfg ? 0 : HALF_CAP;
        const int  cnt  = isfg ? fgc : bgc;
        const int  ci   = isfg ? c : (c - fgc);
        const uint64_t kc = s_cand[base + ci];
        int r = 0;
        for (int j = 0; j < cnt; ++j)
            r += (s_cand[base + j] > kc) ? 1 : 0;
        int slot = -1;
        if (isfg) { if (r < nfg) slot = r; }
        else      { if (r < nbg) slot = nfg + r; }
        if (slot >= 0) {
            int idx = (int)((kc >> 7) & 0x1FFFull);
            int mi  = (int)(kc & 0x7Full);
            float4 bp;
            if (idx < N_PROP)
                bp = *(const float4*)(prop_boxes + ((size_t)b * N_PROP + idx) * 4);
            else
                bp = s_gtb4[idx - N_PROP];
            float area_b;
            {
#pragma clang fp contract(off)
                area_b = (bp.z - bp.x) * (bp.w - bp.y);
            }
            float iou = iou_g(s_gtb4[mi], bp.x, bp.y, bp.z, bp.w, area_b);
            s_out[0][slot] = iou;
            s_out[1][slot] = (float)idx;
            s_out[2][slot] = (float)(isfg ? s_gtc[mi] : NUM_CLASSES_);
            s_out[3][slot] = (float)mi;
        }
    }
    __syncthreads();

    for (int i = tid; i < 5 * BATCH_PER; i += NTF) {
        int o = i / BATCH_PER, p = i % BATCH_PER;
        out[(size_t)o * OUT_STRIDE + (size_t)b * BATCH_PER + p] = s_out[o][p];
    }
}

extern "C" void kernel_launch(void* const* d_in, const int* in_sizes, int n_in,
                              void* d_out, int out_size, void* d_ws, size_t ws_size,
                              hipStream_t stream) {
    const float* gt_boxes   = (const float*)d_in[0];  // [64,100,4]
    const float* prop_boxes = (const float*)d_in[1];  // [64,4000,4]
    const int*   gt_classes = (const int*)  d_in[2];  // [64,100]
    const float* rand_pri   = (const float*)d_in[3];  // [64,4100]
    float* out = (float*)d_out;                       // 5 x [64,512] float32, concat

    const size_t need_ws = (size_t)B_IMG * K_TOT * sizeof(uint64_t);  // 2.1 MB
    if (d_ws != nullptr && ws_size >= need_ws) {
        uint64_t* keys = (uint64_t*)d_ws;
        match_kernel<<<B_IMG * BPI1, NT1, 0, stream>>>(gt_boxes, prop_boxes,
                                                       rand_pri, keys);
        select_kernel<<<B_IMG, NTH, 0, stream>>>(gt_boxes, prop_boxes,
                                                 gt_classes, keys, out);
    } else {
        roiheads_fallback<<<B_IMG, NTF, 0, stream>>>(gt_boxes, prop_boxes,
                                                     gt_classes, rand_pri, out);
    }
}

// Round 2
// 102.752 us; speedup vs baseline: 1.0435x; 1.0435x over previous
//
#include <hip/hip_runtime.h>
#include <stdint.h>

// Problem constants (fixed by the reference)
#define B_IMG        64
#define M_GT         100
#define N_PROP       4000
#define K_TOT        4100          // N + M (proposal_append_gt)
#define NUM_CLASSES_ 80
#define BATCH_PER    512
#define NUM_FG_TGT   128
#define OUT_STRIDE   (B_IMG * BATCH_PER)   // 32768 elements per output tensor

// Kernel 1 (match) geometry: 2-lane m-split, 2112 blocks x 256 threads.
// R14: reverted to R0's proven 33-blocks/image grid (R13's exact-2048 grid
// with a second inlined match_one call site regressed +4.3us — doubled body
// under the 64-VGPR launch_bounds cap).
#define NT1          256
#define BPI1         33                    // blocks per image (33*128 >= 4100)
#define EPB1         128                   // elements per block (2 lanes/elem)
// Kernel 2 (select) geometry
#define NTH          1024
#define HALF_CAP     1024
#define NTF          1024                  // fallback kernel threads

// Key packing (uint64 compare gives exact (fg, pri, idx) descending order;
// midx rides in the low bits — idx is unique so it never affects ordering):
//   bit 50      : fg flag
//   bits 49..20 : float bits of priority (pri in [0,1) => bits < 2^30)
//   bits 19..7  : element index (0..4099 < 8192)  — reproduces the reversed-
//                 stable-argsort tiebreak (higher idx first on equal pri)
//   bits  6..0  : matched gt index (0..99 < 128)

// IoU, contraction off, branchless: uni > 0 always (box wh >= 8 => areas > 0)
// and inter==0 gives +0.0/uni == +0.0 — bit-identical to the reference's
// where(inter>0, inter/uni, 0). Validated absmax-0 in R12.
__device__ __forceinline__ float iou_g(float4 g,
                                       float bx1, float by1, float bx2, float by2,
                                       float area_b) {
#pragma clang fp contract(off)
    float area_a = (g.z - g.x) * (g.w - g.y);
    float ltx = fmaxf(g.x, bx1), lty = fmaxf(g.y, by1);
    float rbx = fminf(g.z, bx2), rby = fminf(g.w, by2);
    float wx = fmaxf(rbx - ltx, 0.0f);
    float wy = fmaxf(rby - lty, 0.0f);
    float inter = wx * wy;
    float uni = area_a + area_b - inter;
    return inter / uni;
}

// Same fp ops, area_a supplied (precomputed once per gt box with the
// identical (z-x)*(w-y) contract-off expression => bit-identical result,
// saves 3 VALU instrs per inner-loop iteration in match).
__device__ __forceinline__ float iou_area(float4 g, float area_a,
                                          float bx1, float by1, float bx2, float by2,
                                          float area_b) {
#pragma clang fp contract(off)
    float ltx = fmaxf(g.x, bx1), lty = fmaxf(g.y, by1);
    float rbx = fminf(g.z, bx2), rby = fminf(g.w, by2);
    float wx = fmaxf(rbx - ltx, 0.0f);
    float wy = fmaxf(rby - lty, 0.0f);
    float inter = wx * wy;
    float uni = area_a + area_b - inter;
    return inter / uni;
}

// ---------------------------------------------------------------------------
// Kernel 1: IoU argmax + key build. Grid = 64 x 33 blocks x 256 threads.
// 2 lanes per element (lane parity picks m in [0,50) / [50,100)); one
// __shfl_xor combines — upper half wins only on strict > == sequential
// first-occurrence argmax (validated absmax-0 in R12). 8 blocks/CU at 2 KB
// LDS => ~8 concurrent divide-chains per SIMD, C=50 — hides the ~600-cycle
// per-iteration dependent chain that latency-bound R4-R12.
// Key stores are AGENT-COHERENT: visibility to kernel 2 does not depend on
// runtime inter-kernel cache maintenance (which graph replay elides — the
// diagnosed cause of R3's replay-only divergence with plain stores).
// ---------------------------------------------------------------------------
__global__ __launch_bounds__(NT1, 8) void match_kernel(
        const float* __restrict__ gt_boxes,    // [B, M, 4]
        const float* __restrict__ prop_boxes,  // [B, N, 4]
        const float* __restrict__ rand_pri,    // [B, K]
        uint64_t*    __restrict__ keys)        // [B, K] ws
{
    __shared__ float4 s_gtb4[M_GT];            // 1.6 KB
    __shared__ float  s_area[M_GT];            // 0.4 KB

    const int blk = blockIdx.x;
    const int b   = blk / BPI1;                // image
    const int q   = blk % BPI1;                // slice
    const int tid = threadIdx.x;

    for (int i = tid; i < M_GT; i += NT1) {
        float4 g = ((const float4*)gt_boxes)[(size_t)b * M_GT + i];
        s_gtb4[i] = g;
        {
#pragma clang fp contract(off)
            s_area[i] = (g.z - g.x) * (g.w - g.y);   // bit-identical to per-lane
        }
    }
    __syncthreads();

    const int e    = q * EPB1 + (tid >> 1);    // element id in image
    const int half = tid & 1;                  // 0: m in [0,50), 1: [50,100)
    if (e >= K_TOT) return;                    // shfl pair exits together

    const uint32_t pb = __float_as_uint(rand_pri[(size_t)b * K_TOT + e]);
    float4 bp;
    if (e < N_PROP)
        bp = *(const float4*)(prop_boxes + ((size_t)b * N_PROP + e) * 4);
    else
        bp = s_gtb4[e - N_PROP];
    float area_b;
    {
#pragma clang fp contract(off)
        area_b = (bp.z - bp.x) * (bp.w - bp.y);
    }
    const int mlo = half * (M_GT / 2);
    float best = -1.0f; int bidx = mlo;
#pragma unroll 2
    for (int m = mlo; m < mlo + M_GT / 2; ++m) {
        float iv = iou_area(s_gtb4[m], s_area[m], bp.x, bp.y, bp.z, bp.w, area_b);
        if (iv > best) { best = iv; bidx = m; }    // strict > => first max in half
    }
    // combine halves: upper wins only on strict > (== sequential argmax)
    const float ob = __shfl_xor(best, 1);
    const int   oi = __shfl_xor(bidx, 1);
    if (half == 0) {
        if (ob > best) { best = ob; bidx = oi; }
        const bool fg = best >= 0.5f;
        uint64_t key = (fg ? (1ull << 50) : 0ull)
                     | ((uint64_t)pb << 20)
                     | ((uint64_t)e  << 7)
                     | (uint64_t)bidx;
        __hip_atomic_store(&keys[(size_t)b * K_TOT + e], key,
                           __ATOMIC_RELAXED, __HIP_MEMORY_SCOPE_AGENT);
    }
}

// ---------------------------------------------------------------------------
// Kernel 2: exact top-k select + rank + emit. Grid = 64 blocks x 1024 thr.
// Entry acquire fence invalidates any stale L1/L2 lines this XCD cached in a
// previous graph replay (keys were written coherently by kernel 1; the graph
// edge orders execution).
// R14: the 256-bucket suffix scan is now ONE WAVE per group (4 buckets/lane,
// Kogge-Stone suffix via __shfl_down, zero barriers) instead of 8 Hillis-
// Steele rounds x 2 barriers; nfg/nbg are recomputed per-thread from
// s_hist[g][0] (broadcast LDS read) instead of a tid0-write + barrier.
// Select barrier count: ~21 -> 7 (16 waves/barrier => ~3-5 us saved).
// Compaction is R0's plain per-thread atomicAdd (proven; ballot variant
// reverted with R13).
// ---------------------------------------------------------------------------
__global__ __launch_bounds__(NTH) void select_kernel(
        const float* __restrict__ gt_boxes,    // [B, M, 4]
        const float* __restrict__ prop_boxes,  // [B, N, 4]
        const int*   __restrict__ gt_classes,  // [B, M]
        const uint64_t* __restrict__ keys,     // [B, K] ws
        float*       __restrict__ out)         // 5 x [B, 512] flat
{
    __shared__ uint64_t s_keys[K_TOT];         // 32.8 KB
    __shared__ uint64_t s_cand[2 * HALF_CAP];  // 16 KB: fg half | bg half
    __shared__ int      s_hist[2][256];        // 2 KB
    __shared__ float4   s_gtb4[M_GT];
    __shared__ int      s_gtc[M_GT];
    __shared__ float    s_out[5][BATCH_PER];   // 10 KB staging
    __shared__ int      s_T[2], s_cnt[2];

    const int b   = blockIdx.x;
    const int tid = threadIdx.x;

    __builtin_amdgcn_fence(__ATOMIC_ACQUIRE, "agent");  // drop stale cache lines

    for (int i = tid; i < 512; i += NTH) s_hist[i >> 8][i & 255] = 0;
    if (tid < 2) s_cnt[tid] = 0;
    for (int i = tid; i < M_GT; i += NTH) {
        s_gtb4[i] = ((const float4*)gt_boxes)[(size_t)b * M_GT + i];
        s_gtc[i]  = gt_classes[(size_t)b * M_GT + i];
    }
    __syncthreads();

    // stage keys + histogram per group
    for (int k = tid; k < K_TOT; k += NTH) {
        uint64_t key = keys[(size_t)b * K_TOT + k];
        s_keys[k] = key;
        int g = ((key >> 50) & 1ull) ? 0 : 1;   // 0 = fg, 1 = bg
        uint32_t pbits = (uint32_t)((key >> 20) & 0x3FFFFFFFull);
        int bucket = min(255, (int)(__uint_as_float(pbits) * 256.0f));  // monotone
        atomicAdd(&s_hist[g][bucket], 1);
    }
    __syncthreads();

    // wave-local suffix scan: wave 0 -> group 0, wave 1 -> group 1.
    // lane L owns buckets [4L, 4L+3]; Kogge-Stone inclusive suffix over lane
    // totals, then local back-substitution. No barriers inside.
    if (tid < 128) {
        const int g    = tid >> 6;
        const int lane = tid & 63;
        const int h0 = s_hist[g][4 * lane + 0];
        const int h1 = s_hist[g][4 * lane + 1];
        const int h2 = s_hist[g][4 * lane + 2];
        const int h3 = s_hist[g][4 * lane + 3];
        int incl = h0 + h1 + h2 + h3;
#pragma unroll
        for (int d = 1; d < 64; d <<= 1) {
            int v = __shfl_down(incl, d);
            if (lane + d < 64) incl += v;
        }
        int excl = __shfl_down(incl, 1);        // suffix of lanes > L
        if (lane == 63) excl = 0;
        const int s3 = h3 + excl;
        const int s2 = h2 + s3;
        const int s1 = h1 + s2;
        const int s0 = h0 + s1;
        s_hist[g][4 * lane + 0] = s0;
        s_hist[g][4 * lane + 1] = s1;
        s_hist[g][4 * lane + 2] = s2;
        s_hist[g][4 * lane + 3] = s3;
    }
    __syncthreads();

    // per-thread recompute of needed counts (broadcast LDS reads, no barrier)
    const int fg_total = s_hist[0][0];
    const int bg_total = s_hist[1][0];
    const int nfg = min(NUM_FG_TGT, fg_total);
    const int nbg = min(BATCH_PER - nfg, bg_total);

    // bucket threshold: max t with S[t] >= need (unique crossing)
    if (tid < 512) {
        int g = tid >> 8, t = tid & 255;
        int need = (g == 0) ? nfg : nbg;
        int St  = s_hist[g][t];
        int St1 = (t == 255) ? -1 : s_hist[g][t + 1];
        if (St >= need && St1 < need) s_T[g] = t;
    }
    if (tid < BATCH_PER) {                     // prefill invalid pattern
        s_out[0][tid] = 0.0f; s_out[1][tid] = -1.0f;
        s_out[2][tid] = -1.0f; s_out[3][tid] = -1.0f;
        s_out[4][tid] = (tid < nfg + nbg) ? 1.0f : 0.0f;
    }
    __syncthreads();

    // compaction into disjoint halves (fg -> [0,HALF_CAP), bg -> [HALF_CAP,...))
    for (int k = tid; k < K_TOT; k += NTH) {
        uint64_t key = s_keys[k];
        int g = ((key >> 50) & 1ull) ? 0 : 1;
        uint32_t pbits = (uint32_t)((key >> 20) & 0x3FFFFFFFull);
        int bucket = min(255, (int)(__uint_as_float(pbits) * 256.0f));
        if (bucket >= s_T[g]) {
            int pos = atomicAdd(&s_cnt[g], 1);
            if (pos < HALF_CAP) s_cand[g * HALF_CAP + pos] = key;
        }
    }
    __syncthreads();

    // rank within each half (keys unique -> each slot written exactly once,
    // independent of atomic ordering) and emit
    const int fgc = min(s_cnt[0], HALF_CAP);
    const int bgc = min(s_cnt[1], HALF_CAP);
    for (int c = tid; c < fgc + bgc; c += NTH) {
        const bool isfg = (c < fgc);
        const int  base = isfg ? 0 : HALF_CAP;
        const int  cnt  = isfg ? fgc : bgc;
        const int  ci   = isfg ? c : (c - fgc);
        const uint64_t kc = s_cand[base + ci];
        int r = 0;
        for (int j = 0; j < cnt; ++j)          // broadcast LDS reads
            r += (s_cand[base + j] > kc) ? 1 : 0;
        int slot = -1;
        if (isfg) { if (r < nfg) slot = r; }
        else      { if (r < nbg) slot = nfg + r; }
        if (slot >= 0) {
            int idx = (int)((kc >> 7) & 0x1FFFull);
            int mi  = (int)(kc & 0x7Full);
            float4 bp;
            if (idx < N_PROP)
                bp = *(const float4*)(prop_boxes + ((size_t)b * N_PROP + idx) * 4);
            else
                bp = s_gtb4[idx - N_PROP];
            float area_b;
            {
#pragma clang fp contract(off)
                area_b = (bp.z - bp.x) * (bp.w - bp.y);
            }
            // bit-exact matched_vals[idx]: same fp ops on same inputs as K1
            float iou = iou_g(s_gtb4[mi], bp.x, bp.y, bp.z, bp.w, area_b);
            s_out[0][slot] = iou;
            s_out[1][slot] = (float)idx;
            s_out[2][slot] = (float)(isfg ? s_gtc[mi] : NUM_CLASSES_);
            s_out[3][slot] = (float)mi;
        }
    }
    __syncthreads();

    // coalesced write-out
    for (int i = tid; i < 5 * BATCH_PER; i += NTH) {
        int o = i / BATCH_PER, p = i % BATCH_PER;
        out[(size_t)o * OUT_STRIDE + (size_t)b * BATCH_PER + p] = s_out[o][p];
    }
}

// ---------------------------------------------------------------------------
// Fallback: proven single kernel (one block per image, zero workspace).
// Used only if ws_size is too small for the key buffer. Kept verbatim from
// the R0 baseline (untested path — minimize churn).
// ---------------------------------------------------------------------------
__global__ __launch_bounds__(NTF) void roiheads_fallback(
        const float* __restrict__ gt_boxes,
        const float* __restrict__ prop_boxes,
        const int*   __restrict__ gt_classes,
        const float* __restrict__ rand_pri,
        float*       __restrict__ out)
{
    __shared__ uint64_t s_keys[K_TOT];
    __shared__ uint64_t s_cand[2 * HALF_CAP];
    __shared__ int      s_hist[2][256];
    __shared__ float4   s_gtb4[M_GT];
    __shared__ int      s_gtc[M_GT];
    __shared__ float    s_out[5][BATCH_PER];
    __shared__ int      s_T[2], s_needed[2], s_cnt[2];

    const int b   = blockIdx.x;
    const int tid = threadIdx.x;

    for (int i = tid; i < 512; i += NTF) s_hist[i >> 8][i & 255] = 0;
    if (tid < 2) s_cnt[tid] = 0;
    for (int i = tid; i < M_GT; i += NTF) {
        s_gtb4[i] = ((const float4*)gt_boxes)[(size_t)b * M_GT + i];
        s_gtc[i]  = gt_classes[(size_t)b * M_GT + i];
    }
    __syncthreads();

    for (int k = tid; k < K_TOT; k += NTF) {
        float4 bp;
        if (k < N_PROP)
            bp = *(const float4*)(prop_boxes + ((size_t)b * N_PROP + k) * 4);
        else
            bp = s_gtb4[k - N_PROP];
        float area_b;
        {
#pragma clang fp contract(off)
            area_b = (bp.z - bp.x) * (bp.w - bp.y);
        }
        float best = -1.0f; int bidx = 0;
        for (int m = 0; m < M_GT; ++m) {
            float iv = iou_g(s_gtb4[m], bp.x, bp.y, bp.z, bp.w, area_b);
            if (iv > best) { best = iv; bidx = m; }
        }
        const bool fg = best >= 0.5f;
        const float pri = rand_pri[(size_t)b * K_TOT + k];
        const uint32_t pb = __float_as_uint(pri);
        s_keys[k] = (fg ? (1ull << 50) : 0ull)
                  | ((uint64_t)pb << 20)
                  | ((uint64_t)k  << 7)
                  | (uint64_t)bidx;
        int bucket = min(255, (int)(pri * 256.0f));
        atomicAdd(&s_hist[fg ? 0 : 1][bucket], 1);
    }
    __syncthreads();

    for (int d = 1; d < 256; d <<= 1) {
        int v = 0, g = tid >> 8, t = tid & 255;
        bool act = (tid < 512) && (t + d < 256);
        if (act) v = s_hist[g][t + d];
        __syncthreads();
        if (act) s_hist[g][t] += v;
        __syncthreads();
    }

    if (tid == 0) {
        int fg_total = s_hist[0][0];
        int bg_total = s_hist[1][0];
        int nfg = min(NUM_FG_TGT, fg_total);
        int nbg = min(BATCH_PER - nfg, bg_total);
        s_needed[0] = nfg; s_needed[1] = nbg;
    }
    __syncthreads();

    if (tid < 512) {
        int g = tid >> 8, t = tid & 255;
        int need = s_needed[g];
        int St  = s_hist[g][t];
        int St1 = (t == 255) ? -1 : s_hist[g][t + 1];
        if (St >= need && St1 < need) s_T[g] = t;
    }
    if (tid < BATCH_PER) {
        s_out[0][tid] = 0.0f; s_out[1][tid] = -1.0f;
        s_out[2][tid] = -1.0f; s_out[3][tid] = -1.0f;
    }
    __syncthreads();

    const int nfg = s_needed[0], nbg = s_needed[1];
    if (tid < BATCH_PER)
        s_out[4][tid] = (tid < nfg + nbg) ? 1.0f : 0.0f;

    for (int k = tid; k < K_TOT; k += NTF) {
        uint64_t key = s_keys[k];
        int g = ((key >> 50) & 1ull) ? 0 : 1;
        uint32_t pbits = (uint32_t)((key >> 20) & 0x3FFFFFFFull);
        int bucket = min(255, (int)(__uint_as_float(pbits) * 256.0f));
        if (bucket >= s_T[g]) {
            int pos = atomicAdd(&s_cnt[g], 1);
            if (pos < HALF_CAP) s_cand[g * HALF_CAP + pos] = key;
        }
    }
    __syncthreads();

    const int fgc = min(s_cnt[0], HALF_CAP);
    const int bgc = min(s_cnt[1], HALF_CAP);
    for (int c = tid; c < fgc + bgc; c += NTF) {
        const bool isfg = (c < fgc);
        const int  base = isfg ? 0 : HALF_CAP;
        const int  cnt  = isfg ? fgc : bgc;
        const int  ci   = isfg ? c : (c - fgc);
        const uint64_t kc = s_cand[base + ci];
        int r = 0;
        for (int j = 0; j < cnt; ++j)
            r += (s_cand[base + j] > kc) ? 1 : 0;
        int slot = -1;
        if (isfg) { if (r < nfg) slot = r; }
        else      { if (r < nbg) slot = nfg + r; }
        if (slot >= 0) {
            int idx = (int)((kc >> 7) & 0x1FFFull);
            int mi  = (int)(kc & 0x7Full);
            float4 bp;
            if (idx < N_PROP)
                bp = *(const float4*)(prop_boxes + ((size_t)b * N_PROP + idx) * 4);
            else
                bp = s_gtb4[idx - N_PROP];
            float area_b;
            {
#pragma clang fp contract(off)
                area_b = (bp.z - bp.x) * (bp.w - bp.y);
            }
            float iou = iou_g(s_gtb4[mi], bp.x, bp.y, bp.z, bp.w, area_b);
            s_out[0][slot] = iou;
            s_out[1][slot] = (float)idx;
            s_out[2][slot] = (float)(isfg ? s_gtc[mi] : NUM_CLASSES_);
            s_out[3][slot] = (float)mi;
        }
    }
    __syncthreads();

    for (int i = tid; i < 5 * BATCH_PER; i += NTF) {
        int o = i / BATCH_PER, p = i % BATCH_PER;
        out[(size_t)o * OUT_STRIDE + (size_t)b * BATCH_PER + p] = s_out[o][p];
    }
}

extern "C" void kernel_launch(void* const* d_in, const int* in_sizes, int n_in,
                              void* d_out, int out_size, void* d_ws, size_t ws_size,
                              hipStream_t stream) {
    const float* gt_boxes   = (const float*)d_in[0];  // [64,100,4]
    const float* prop_boxes = (const float*)d_in[1];  // [64,4000,4]
    const int*   gt_classes = (const int*)  d_in[2];  // [64,100]
    const float* rand_pri   = (const float*)d_in[3];  // [64,4100]
    float* out = (float*)d_out;                       // 5 x [64,512] float32, concat

    const size_t need_ws = (size_t)B_IMG * K_TOT * sizeof(uint64_t);  // 2.1 MB
    if (d_ws != nullptr && ws_size >= need_ws) {
        uint64_t* keys = (uint64_t*)d_ws;
        match_kernel<<<B_IMG * BPI1, NT1, 0, stream>>>(gt_boxes, prop_boxes,
                                                       rand_pri, keys);
        select_kernel<<<B_IMG, NTH, 0, stream>>>(gt_boxes, prop_boxes,
                                                 gt_classes, keys, out);
    } else {
        roiheads_fallback<<<B_IMG, NTF, 0, stream>>>(gt_boxes, prop_boxes,
                                                     gt_classes, rand_pri, out);
    }
}